// Round 6
// baseline (311.217 us; speedup 1.0000x reference)
//
#include <hip/hip_runtime.h>

#define EPS 1e-10f
#define BLOCK 256
#define GRID1 1024
#define NTHREADS (GRID1 * BLOCK)     // 262144 threads
#define ITERG (NTHREADS * 4)         // groups consumed per full iteration

// R10. R9 null (grid 2048->1024 identical): stream count not the limiter.
// R5 null: MLP depth not the limiter. Still 4.16 TB/s read vs 6.8 TB/s
// memset write on the same chip. Last unisolated variable: block->address
// mapping. Since R4, each block owns a private 16KB chunk -> instantaneous
// read window = 1024 scattered regions over 320MB -> DRAM row-buffer churn.
// R10 single change: fine interleave (adjacent blocks on adjacent addresses;
// per unroll-step the whole grid reads ONE contiguous 4MB window, marching
// linearly) -- the memset/copy access shape. nt loads, swizzle, GRID, reduce
// all held fixed. Null => ROOFLINE (nt 2-stream read ceiling ~4.2 TB/s;
// wall dominated by ~220us harness reset memsets).

typedef float f32x4 __attribute__((ext_vector_type(4)));
typedef int   i32x4 __attribute__((ext_vector_type(4)));

__global__ __launch_bounds__(BLOCK) void sparse_loss_stage1(
    const float* __restrict__ pred,
    const int* __restrict__ y,
    const int* __restrict__ lamda_p,
    float* __restrict__ partials,   // [GRID1]
    long long nvec,                 // number of float4 groups
    long long total) {              // total element count
  const float lam = (float)(*lamda_p);
  float acc = 0.0f;  // accumulates +coef*log(arg); sign applied in stage 2

  const f32x4* __restrict__ pv = reinterpret_cast<const f32x4*>(pred);
  const i32x4* __restrict__ yv = reinterpret_cast<const i32x4*>(y);

  // Bijective XCD-chunked swizzle (1024 % 8 == 0).
  const int bid = (int)((blockIdx.x & 7) * (GRID1 / 8) + (blockIdx.x >> 3));

#define ELEM(P, Y)                                   \
  {                                                  \
    const bool z = ((Y) == 0);                       \
    const float a = EPS + (z ? (1.0f - (P)) : (P));  \
    const float c = z ? 1.0f : lam;                  \
    acc = fmaf(c, __logf(a), acc);                   \
  }
#define ELEM4(A, B) ELEM(A[0], B[0]) ELEM(A[1], B[1]) ELEM(A[2], B[2]) ELEM(A[3], B[3])

#define ELEMM(P, Y, M)                               \
  {                                                  \
    const bool z = ((Y) == 0);                       \
    const float a = EPS + (z ? (1.0f - (P)) : (P));  \
    const float c = (z ? 1.0f : lam) * (M);          \
    acc = fmaf(c, __logf(a), acc);                   \
  }
#define ELEM4M(A, B, M) \
  ELEMM(A[0], B[0], M) ELEMM(A[1], B[1], M) ELEMM(A[2], B[2], M) ELEMM(A[3], B[3], M)

  const long long nfull = nvec / ITERG;          // full fine-interleaved iters
  const long long j0 = (long long)bid * BLOCK + threadIdx.x;

  // ---- full iterations: per unroll-step k the ENTIRE grid reads one
  //      contiguous 4MB window (adjacent blocks -> adjacent addresses) ----
  for (long long s = 0; s < nfull; ++s) {
    const long long b = s * ITERG + j0;
    f32x4 a0, a1, a2, a3;
    i32x4 q0, q1, q2, q3;
    a0 = __builtin_nontemporal_load(pv + b);
    a1 = __builtin_nontemporal_load(pv + b + NTHREADS);
    a2 = __builtin_nontemporal_load(pv + b + 2 * NTHREADS);
    a3 = __builtin_nontemporal_load(pv + b + 3 * NTHREADS);
    q0 = __builtin_nontemporal_load(yv + b);
    q1 = __builtin_nontemporal_load(yv + b + NTHREADS);
    q2 = __builtin_nontemporal_load(yv + b + 2 * NTHREADS);
    q3 = __builtin_nontemporal_load(yv + b + 3 * NTHREADS);
    ELEM4(a0, q0)
    ELEM4(a1, q1)
    ELEM4(a2, q2)
    ELEM4(a3, q3)
  }

  // ---- masked remainder iterations (same fine-interleaved shape) ----
  for (long long rbase = nfull * ITERG; rbase < nvec; rbase += ITERG) {
    const long long b = rbase + j0;
    const long long jA = b, jB = b + NTHREADS, jC = b + 2 * NTHREADS,
                    jD = b + 3 * NTHREADS;
    const float mA = (jA < nvec) ? 1.0f : 0.0f;
    const float mB = (jB < nvec) ? 1.0f : 0.0f;
    const float mC = (jC < nvec) ? 1.0f : 0.0f;
    const float mD = (jD < nvec) ? 1.0f : 0.0f;
    const long long cA = (jA < nvec) ? jA : 0;
    const long long cB = (jB < nvec) ? jB : 0;
    const long long cC = (jC < nvec) ? jC : 0;
    const long long cD = (jD < nvec) ? jD : 0;
    f32x4 a0, a1, a2, a3;
    i32x4 q0, q1, q2, q3;
    a0 = __builtin_nontemporal_load(pv + cA);
    a1 = __builtin_nontemporal_load(pv + cB);
    a2 = __builtin_nontemporal_load(pv + cC);
    a3 = __builtin_nontemporal_load(pv + cD);
    q0 = __builtin_nontemporal_load(yv + cA);
    q1 = __builtin_nontemporal_load(yv + cB);
    q2 = __builtin_nontemporal_load(yv + cC);
    q3 = __builtin_nontemporal_load(yv + cD);
    ELEM4M(a0, q0, mA)
    ELEM4M(a1, q1, mB)
    ELEM4M(a2, q2, mC)
    ELEM4M(a3, q3, mD)
  }

  // ---- scalar tail (total % 4 != 0 -- not the case here, but cheap) ----
  const long long gtid = (long long)bid * BLOCK + threadIdx.x;
  const long long gstride = (long long)gridDim.x * BLOCK;
  for (long long j = nvec * 4 + gtid; j < total; j += gstride) {
    const float p = pred[j];
    ELEM(p, y[j])
  }
#undef ELEM
#undef ELEM4
#undef ELEMM
#undef ELEM4M

  // wave64 butterfly reduce
  for (int off = 32; off > 0; off >>= 1)
    acc += __shfl_down(acc, off, 64);

  __shared__ float ssum[4];
  const int lane = threadIdx.x & 63;
  const int wave = threadIdx.x >> 6;
  if (lane == 0) ssum[wave] = acc;
  __syncthreads();

  if (threadIdx.x == 0)
    partials[bid] = ssum[0] + ssum[1] + ssum[2] + ssum[3];
}

__global__ __launch_bounds__(BLOCK) void sparse_loss_stage2(
    const float* __restrict__ partials,  // [GRID1]
    float* __restrict__ out,
    float inv_total) {
  float acc = 0.0f;
  for (int i = threadIdx.x; i < GRID1; i += BLOCK)
    acc += partials[i];

  for (int off = 32; off > 0; off >>= 1)
    acc += __shfl_down(acc, off, 64);

  __shared__ float ssum[4];
  const int lane = threadIdx.x & 63;
  const int wave = threadIdx.x >> 6;
  if (lane == 0) ssum[wave] = acc;
  __syncthreads();

  if (threadIdx.x == 0)
    out[0] = -(ssum[0] + ssum[1] + ssum[2] + ssum[3]) * inv_total;
}

extern "C" void kernel_launch(void* const* d_in, const int* in_sizes, int n_in,
                              void* d_out, int out_size, void* d_ws, size_t ws_size,
                              hipStream_t stream) {
  const float* pred = (const float*)d_in[0];
  const int* y = (const int*)d_in[1];
  const int* lamda = (const int*)d_in[2];
  float* out = (float*)d_out;
  float* partials = (float*)d_ws;  // 1024 floats = 4 KB scratch

  const long long total = (long long)in_sizes[0];
  const long long nvec = total / 4;
  const float inv_total = 1.0f / (float)total;

  sparse_loss_stage1<<<GRID1, BLOCK, 0, stream>>>(pred, y, lamda, partials,
                                                  nvec, total);
  sparse_loss_stage2<<<1, BLOCK, 0, stream>>>(partials, out, inv_total);
}

// Round 7
// 301.016 us; speedup vs baseline: 1.0339x; 1.0339x over previous
//
#include <hip/hip_runtime.h>

#define EPS 1e-10f
#define BLOCK 256
#define GRID1 1024
#define BGROUPS 1024  // float4 groups per block per sweep (= 4 * BLOCK)

// R11. R10 post-mortem: fine interleave REGRESSED (stage1 79->88us) ->
// chunked mapping restored. Evidence ladder: normal 2.80 -> pred-nt 3.39 ->
// both-nt 4.16 TB/s, memset 6.8 TB/s same chip. Only cache-path shaping has
// ever moved this kernel -> residual limiter = L2 line-fill/allocation on
// reads (nt still allocates; 4.16 TB/s = ~1.7 fills/cy/XCD).
// R11 single change vs R9: buffer_load_dwordx4 with sc0 sc1 nt (full L1+L2
// bypass, gfx950 MUBUF cache-policy flags). SRD per HK T8; 32-bit voffsets
// (163.84MB buffers); R5-proven asm shape (8 issues, one vmcnt(0) drain).
// Null/regression => cache lever exhausted => ROOFLINE next round.

typedef float f32x4 __attribute__((ext_vector_type(4)));
typedef int   i32x4 __attribute__((ext_vector_type(4)));

static __device__ __forceinline__ i32x4 make_srd(const void* p, unsigned bytes) {
  union { unsigned u[4]; i32x4 v; } s;
  s.u[0] = (unsigned)(unsigned long long)p;
  s.u[1] = (unsigned)(((unsigned long long)p) >> 32);  // stride=0
  s.u[2] = bytes;                                      // num_records (bytes)
  s.u[3] = 0x00020000u;                                // raw dword config
  return s.v;
}

// Load 16B via SRD, bypassing L1 (sc0) and L2 (sc1), non-temporal (nt).
#define BLOAD(dst, srd, voff)                                        \
  asm volatile("buffer_load_dwordx4 %0, %1, %2, 0 offen sc0 sc1 nt"  \
               : "=v"(dst) : "v"(voff), "s"(srd))

__global__ __launch_bounds__(BLOCK) void sparse_loss_stage1(
    const float* __restrict__ pred,
    const int* __restrict__ y,
    const int* __restrict__ lamda_p,
    float* __restrict__ partials,   // [GRID1]
    long long nvec,                 // number of float4 groups
    long long total) {              // total element count
  const float lam = (float)(*lamda_p);
  float acc = 0.0f;  // accumulates +coef*log(arg); sign applied in stage 2

  const i32x4 sp = make_srd(pred, (unsigned)(nvec * 16));
  const i32x4 sy = make_srd(y,    (unsigned)(nvec * 16));

  // Bijective XCD-chunked swizzle (1024 % 8 == 0).
  const int bid = (int)((blockIdx.x & 7) * (GRID1 / 8) + (blockIdx.x >> 3));

#define ELEM(P, Y)                                   \
  {                                                  \
    const bool z = ((Y) == 0);                       \
    const float a = EPS + (z ? (1.0f - (P)) : (P));  \
    const float c = z ? 1.0f : lam;                  \
    acc = fmaf(c, __logf(a), acc);                   \
  }
#define ELEM4(A, B) ELEM(A[0], B[0]) ELEM(A[1], B[1]) ELEM(A[2], B[2]) ELEM(A[3], B[3])

#define ELEMM(P, Y, M)                               \
  {                                                  \
    const bool z = ((Y) == 0);                       \
    const float a = EPS + (z ? (1.0f - (P)) : (P));  \
    const float c = (z ? 1.0f : lam) * (M);          \
    acc = fmaf(c, __logf(a), acc);                   \
  }
#define ELEM4M(A, B, M) \
  ELEMM(A[0], B[0], M) ELEMM(A[1], B[1], M) ELEMM(A[2], B[2], M) ELEMM(A[3], B[3], M)

  const long long SWEEP = (long long)GRID1 * BGROUPS;  // groups per full sweep
  const long long nfull = nvec / SWEEP;
  const long long j0 = (long long)bid * BGROUPS + threadIdx.x;

  // ---- full sweeps: 8 L2-bypassing dwordx4 loads in flight, one drain ----
  for (long long s = 0; s < nfull; ++s) {
    const long long b = s * SWEEP + j0;
    const unsigned vb = (unsigned)b * 16u;  // byte voffset, fits u32
    f32x4 a0, a1, a2, a3;
    i32x4 q0, q1, q2, q3;
    BLOAD(a0, sp, vb);
    BLOAD(a1, sp, vb + 256u * 16u);
    BLOAD(a2, sp, vb + 512u * 16u);
    BLOAD(a3, sp, vb + 768u * 16u);
    BLOAD(q0, sy, vb);
    BLOAD(q1, sy, vb + 256u * 16u);
    BLOAD(q2, sy, vb + 512u * 16u);
    BLOAD(q3, sy, vb + 768u * 16u);
    asm volatile("s_waitcnt vmcnt(0)" ::: "memory");
    __builtin_amdgcn_sched_barrier(0);
    ELEM4(a0, q0)
    ELEM4(a1, q1)
    ELEM4(a2, q2)
    ELEM4(a3, q3)
  }

  // ---- predicated remainder sweep (index-clamped, coef-masked) ----
  const long long rb = nfull * SWEEP;
  if (rb + (long long)bid * BGROUPS < nvec) {
    const long long b = rb + j0;
    const long long jA = b, jB = b + 256, jC = b + 512, jD = b + 768;
    const float mA = (jA < nvec) ? 1.0f : 0.0f;
    const float mB = (jB < nvec) ? 1.0f : 0.0f;
    const float mC = (jC < nvec) ? 1.0f : 0.0f;
    const float mD = (jD < nvec) ? 1.0f : 0.0f;
    const unsigned vA = (unsigned)((jA < nvec) ? jA : 0) * 16u;
    const unsigned vB = (unsigned)((jB < nvec) ? jB : 0) * 16u;
    const unsigned vC = (unsigned)((jC < nvec) ? jC : 0) * 16u;
    const unsigned vD = (unsigned)((jD < nvec) ? jD : 0) * 16u;
    f32x4 a0, a1, a2, a3;
    i32x4 q0, q1, q2, q3;
    BLOAD(a0, sp, vA);
    BLOAD(a1, sp, vB);
    BLOAD(a2, sp, vC);
    BLOAD(a3, sp, vD);
    BLOAD(q0, sy, vA);
    BLOAD(q1, sy, vB);
    BLOAD(q2, sy, vC);
    BLOAD(q3, sy, vD);
    asm volatile("s_waitcnt vmcnt(0)" ::: "memory");
    __builtin_amdgcn_sched_barrier(0);
    ELEM4M(a0, q0, mA)
    ELEM4M(a1, q1, mB)
    ELEM4M(a2, q2, mC)
    ELEM4M(a3, q3, mD)
  }

  // ---- scalar tail (total % 4 != 0 -- not the case here, but cheap) ----
  const long long gtid = (long long)bid * BLOCK + threadIdx.x;
  const long long gstride = (long long)gridDim.x * BLOCK;
  for (long long j = nvec * 4 + gtid; j < total; j += gstride) {
    const float p = pred[j];
    ELEM(p, y[j])
  }
#undef ELEM
#undef ELEM4
#undef ELEMM
#undef ELEM4M

  // wave64 butterfly reduce
  for (int off = 32; off > 0; off >>= 1)
    acc += __shfl_down(acc, off, 64);

  __shared__ float ssum[4];
  const int lane = threadIdx.x & 63;
  const int wave = threadIdx.x >> 6;
  if (lane == 0) ssum[wave] = acc;
  __syncthreads();

  if (threadIdx.x == 0)
    partials[bid] = ssum[0] + ssum[1] + ssum[2] + ssum[3];
}

__global__ __launch_bounds__(BLOCK) void sparse_loss_stage2(
    const float* __restrict__ partials,  // [GRID1]
    float* __restrict__ out,
    float inv_total) {
  float acc = 0.0f;
  for (int i = threadIdx.x; i < GRID1; i += BLOCK)
    acc += partials[i];

  for (int off = 32; off > 0; off >>= 1)
    acc += __shfl_down(acc, off, 64);

  __shared__ float ssum[4];
  const int lane = threadIdx.x & 63;
  const int wave = threadIdx.x >> 6;
  if (lane == 0) ssum[wave] = acc;
  __syncthreads();

  if (threadIdx.x == 0)
    out[0] = -(ssum[0] + ssum[1] + ssum[2] + ssum[3]) * inv_total;
}

extern "C" void kernel_launch(void* const* d_in, const int* in_sizes, int n_in,
                              void* d_out, int out_size, void* d_ws, size_t ws_size,
                              hipStream_t stream) {
  const float* pred = (const float*)d_in[0];
  const int* y = (const int*)d_in[1];
  const int* lamda = (const int*)d_in[2];
  float* out = (float*)d_out;
  float* partials = (float*)d_ws;  // 1024 floats = 4 KB scratch

  const long long total = (long long)in_sizes[0];
  const long long nvec = total / 4;
  const float inv_total = 1.0f / (float)total;

  sparse_loss_stage1<<<GRID1, BLOCK, 0, stream>>>(pred, y, lamda, partials,
                                                  nvec, total);
  sparse_loss_stage2<<<1, BLOCK, 0, stream>>>(partials, out, inv_total);
}